// Round 1
// baseline (8094.843 us; speedup 1.0000x reference)
//
#include <hip/hip_runtime.h>

#define NN 100000
#define NE 1600000
#define SF 16      // static feats
#define DF 32      // dynamic feats
#define EFT 8      // edge feats
#define INF_ 104   // 2*SF + 2*DF + EFT
#define HF 64      // hidden

// ---------------- init: out = x_t @ F[0] ----------------
__global__ __launch_bounds__(256) void init_kernel(
    const float* __restrict__ x_t, const float* __restrict__ F0,
    float* __restrict__ out) {
  int n = blockIdx.x * blockDim.x + threadIdx.x;
  if (n >= NN) return;
  float x[DF];
  const float4* xr = reinterpret_cast<const float4*>(x_t + (size_t)n * DF);
#pragma unroll
  for (int q = 0; q < 8; ++q) {
    float4 v = xr[q];
    x[4*q+0]=v.x; x[4*q+1]=v.y; x[4*q+2]=v.z; x[4*q+3]=v.w;
  }
  float4* orow = reinterpret_cast<float4*>(out + (size_t)n * DF);
#pragma unroll
  for (int q = 0; q < 8; ++q) {
    float4 acc = {0.f, 0.f, 0.f, 0.f};
#pragma unroll
    for (int i = 0; i < DF; ++i) {
      float xi = x[i];
      acc.x = fmaf(xi, F0[i*DF + 4*q+0], acc.x);
      acc.y = fmaf(xi, F0[i*DF + 4*q+1], acc.y);
      acc.z = fmaf(xi, F0[i*DF + 4*q+2], acc.z);
      acc.w = fmaf(xi, F0[i*DF + 4*q+3], acc.w);
    }
    orow[q] = acc;
  }
}

// ---------------- edge MLP + scatter ----------------
__global__ __launch_bounds__(256) void edge_kernel(
    const float* __restrict__ x_s, const float* __restrict__ out,
    const int* __restrict__ ei, const float* __restrict__ ea,
    const float* __restrict__ W1, const float* __restrict__ b1,
    const float* __restrict__ W2, const float* __restrict__ b2,
    float* __restrict__ scattered) {
  int e = blockIdx.x * blockDim.x + threadIdx.x;
  if (e >= NE) return;
  int r = ei[e];
  int c = ei[NE + e];

  float ef[INF_];
  {  // xs_row -> ef[0..15]
    const float4* p = reinterpret_cast<const float4*>(x_s + (size_t)r * SF);
#pragma unroll
    for (int q = 0; q < 4; ++q) {
      float4 v = p[q];
      ef[4*q+0]=v.x; ef[4*q+1]=v.y; ef[4*q+2]=v.z; ef[4*q+3]=v.w;
    }
  }
  {  // xs_col -> ef[16..31]
    const float4* p = reinterpret_cast<const float4*>(x_s + (size_t)c * SF);
#pragma unroll
    for (int q = 0; q < 4; ++q) {
      float4 v = p[q];
      ef[16+4*q+0]=v.x; ef[16+4*q+1]=v.y; ef[16+4*q+2]=v.z; ef[16+4*q+3]=v.w;
    }
  }
  {  // out_row -> ef[32..63]
    const float4* p = reinterpret_cast<const float4*>(out + (size_t)r * DF);
#pragma unroll
    for (int q = 0; q < 8; ++q) {
      float4 v = p[q];
      ef[32+4*q+0]=v.x; ef[32+4*q+1]=v.y; ef[32+4*q+2]=v.z; ef[32+4*q+3]=v.w;
    }
  }
  {  // out_col -> ef[64..95]
    const float4* p = reinterpret_cast<const float4*>(out + (size_t)c * DF);
#pragma unroll
    for (int q = 0; q < 8; ++q) {
      float4 v = p[q];
      ef[64+4*q+0]=v.x; ef[64+4*q+1]=v.y; ef[64+4*q+2]=v.z; ef[64+4*q+3]=v.w;
    }
  }
  {  // edge_attr -> ef[96..103]
    const float4* p = reinterpret_cast<const float4*>(ea + (size_t)e * EFT);
#pragma unroll
    for (int q = 0; q < 2; ++q) {
      float4 v = p[q];
      ef[96+4*q+0]=v.x; ef[96+4*q+1]=v.y; ef[96+4*q+2]=v.z; ef[96+4*q+3]=v.w;
    }
  }

  // edge mask from node row-sums (mask[n] = sum(out[n,:]) != 0)
  float sr = 0.f, sc = 0.f;
#pragma unroll
  for (int j = 0; j < DF; ++j) { sr += ef[32+j]; sc += ef[64+j]; }
  float em = (sr != 0.f || sc != 0.f) ? 1.f : 0.f;

  // MLP: o = relu(ef @ W1 + b1) @ W2 + b2, hidden in 4 chunks of 16
  float o[DF];
#pragma unroll
  for (int j = 0; j < DF; ++j) o[j] = b2[j];

#pragma unroll 1
  for (int c4 = 0; c4 < 4; ++c4) {
    float h[16];
    const float* b1p = b1 + c4 * 16;
#pragma unroll
    for (int jj = 0; jj < 16; ++jj) h[jj] = b1p[jj];
    const float* w1p = W1 + c4 * 16;
#pragma unroll
    for (int i = 0; i < INF_; ++i) {
      float x = ef[i];
#pragma unroll
      for (int jj = 0; jj < 16; ++jj)
        h[jj] = fmaf(x, w1p[i*HF + jj], h[jj]);
    }
    const float* w2p = W2 + c4 * 16 * DF;
#pragma unroll
    for (int jj = 0; jj < 16; ++jj) {
      float hr = h[jj] > 0.f ? h[jj] : 0.f;
#pragma unroll
      for (int j = 0; j < DF; ++j)
        o[j] = fmaf(hr, w2p[jj*DF + j], o[j]);
    }
  }

  // L2 normalize (zero if zero norm)
  float nsq = 0.f;
#pragma unroll
  for (int j = 0; j < DF; ++j) nsq = fmaf(o[j], o[j], nsq);
  float scale = (nsq > 0.f) ? rsqrtf(nsq) : 0.f;
  float ms = scale * em;

  // shift = (out_col - out_row) * w * em, scatter-add into scattered[col]
  float* dst = scattered + (size_t)c * DF;
#pragma unroll
  for (int j = 0; j < DF; ++j) {
    float shift = (ef[64+j] - ef[32+j]) * o[j] * ms;
    unsafeAtomicAdd(&dst[j], shift);
  }
}

// ---------------- node update: out += scattered @ F[k+1]; scattered = 0 ----
__global__ __launch_bounds__(256) void node_kernel(
    float* __restrict__ out, float* __restrict__ scattered,
    const float* __restrict__ Fk) {
  int n = blockIdx.x * blockDim.x + threadIdx.x;
  if (n >= NN) return;
  float s[DF];
  float4* sp = reinterpret_cast<float4*>(scattered + (size_t)n * DF);
#pragma unroll
  for (int q = 0; q < 8; ++q) {
    float4 v = sp[q];
    s[4*q+0]=v.x; s[4*q+1]=v.y; s[4*q+2]=v.z; s[4*q+3]=v.w;
  }
  float4* op = reinterpret_cast<float4*>(out + (size_t)n * DF);
#pragma unroll
  for (int q = 0; q < 8; ++q) {
    float4 acc = op[q];
#pragma unroll
    for (int i = 0; i < DF; ++i) {
      float si = s[i];
      acc.x = fmaf(si, Fk[i*DF + 4*q+0], acc.x);
      acc.y = fmaf(si, Fk[i*DF + 4*q+1], acc.y);
      acc.z = fmaf(si, Fk[i*DF + 4*q+2], acc.z);
      acc.w = fmaf(si, Fk[i*DF + 4*q+3], acc.w);
    }
    op[q] = acc;
  }
  float4 z = {0.f, 0.f, 0.f, 0.f};
#pragma unroll
  for (int q = 0; q < 8; ++q) sp[q] = z;
}

extern "C" void kernel_launch(void* const* d_in, const int* in_sizes, int n_in,
                              void* d_out, int out_size, void* d_ws, size_t ws_size,
                              hipStream_t stream) {
  const float* x_s = (const float*)d_in[0];
  const float* x_t = (const float*)d_in[1];
  const int*   ei  = (const int*)d_in[2];
  const float* ea  = (const float*)d_in[3];
  const float* W1  = (const float*)d_in[4];
  const float* b1  = (const float*)d_in[5];
  const float* W2  = (const float*)d_in[6];
  const float* b2  = (const float*)d_in[7];
  const float* F   = (const float*)d_in[8];

  float* out = (float*)d_out;
  float* scattered = (float*)d_ws;

  hipMemsetAsync(scattered, 0, (size_t)NN * DF * sizeof(float), stream);

  dim3 blk(256);
  dim3 grid_n((NN + 255) / 256);
  dim3 grid_e((NE + 255) / 256);

  init_kernel<<<grid_n, blk, 0, stream>>>(x_t, F, out);
  for (int k = 0; k < 2; ++k) {
    edge_kernel<<<grid_e, blk, 0, stream>>>(x_s, out, ei, ea, W1, b1, W2, b2,
                                            scattered);
    node_kernel<<<grid_n, blk, 0, stream>>>(out, scattered,
                                            F + (size_t)(k + 1) * DF * DF);
  }
}

// Round 2
// 1545.857 us; speedup vs baseline: 5.2365x; 5.2365x over previous
//
#include <hip/hip_runtime.h>

#define NN 100000
#define NE 1600000
#define SF 16
#define DF 32
#define EFT 8
#define HF 64

// ---------------- CSR build ----------------
__global__ __launch_bounds__(256) void hist_kernel(const int* __restrict__ ei,
                                                   int* __restrict__ deg) {
  int e = blockIdx.x * 256 + threadIdx.x;
  if (e < NE) atomicAdd(&deg[ei[NE + e]], 1);
}

__global__ __launch_bounds__(256) void scan1_kernel(const int* __restrict__ deg,
                                                    int* __restrict__ cur,
                                                    int* __restrict__ bsums) {
  __shared__ int ts[256];
  int tid = threadIdx.x;
  int base = blockIdx.x * 1024 + tid * 4;
  int v[4];
#pragma unroll
  for (int q = 0; q < 4; ++q) v[q] = (base + q < NN) ? deg[base + q] : 0;
  int s = v[0] + v[1] + v[2] + v[3];
  ts[tid] = s;
  __syncthreads();
  for (int off = 1; off < 256; off <<= 1) {
    int t = (tid >= off) ? ts[tid - off] : 0;
    __syncthreads();
    ts[tid] += t;
    __syncthreads();
  }
  int excl = ts[tid] - s;
  if (tid == 255) bsums[blockIdx.x] = ts[255];
  int run = excl;
#pragma unroll
  for (int q = 0; q < 4; ++q) {
    if (base + q < NN) cur[base + q] = run;
    run += v[q];
  }
}

__global__ void scan2_kernel(int* __restrict__ bsums, int nb) {
  int acc = 0;
  for (int i = 0; i < nb; ++i) { int t = bsums[i]; bsums[i] = acc; acc += t; }
}

__global__ __launch_bounds__(256) void scan3_kernel(int* __restrict__ cur,
                                                    const int* __restrict__ bsums) {
  int i = blockIdx.x * 256 + threadIdx.x;
  if (i < NN) cur[i] += bsums[i >> 10];
}

__global__ __launch_bounds__(256) void fill_kernel(const int* __restrict__ ei,
                                                   int* __restrict__ cur,
                                                   int* __restrict__ row_s,
                                                   int* __restrict__ col_s,
                                                   int* __restrict__ eid_s) {
  int e = blockIdx.x * 256 + threadIdx.x;
  if (e >= NE) return;
  int r = ei[e];
  int c = ei[NE + e];
  int pos = atomicAdd(&cur[c], 1);
  row_s[pos] = r;
  col_s[pos] = c;
  eid_s[pos] = e;
}

// ---------------- init: out = x_t @ F[0] ----------------
__global__ __launch_bounds__(256) void init_kernel(
    const float* __restrict__ x_t, const float* __restrict__ F0,
    float* __restrict__ out) {
  int n = blockIdx.x * 256 + threadIdx.x;
  if (n >= NN) return;
  float x[DF];
  const float4* xr = reinterpret_cast<const float4*>(x_t + (size_t)n * DF);
#pragma unroll
  for (int q = 0; q < 8; ++q) {
    float4 v = xr[q];
    x[4*q+0]=v.x; x[4*q+1]=v.y; x[4*q+2]=v.z; x[4*q+3]=v.w;
  }
  float4* orow = reinterpret_cast<float4*>(out + (size_t)n * DF);
#pragma unroll
  for (int q = 0; q < 8; ++q) {
    float4 acc = {0.f, 0.f, 0.f, 0.f};
#pragma unroll
    for (int i = 0; i < DF; ++i) {
      float xi = x[i];
      acc.x = fmaf(xi, F0[i*DF + 4*q+0], acc.x);
      acc.y = fmaf(xi, F0[i*DF + 4*q+1], acc.y);
      acc.z = fmaf(xi, F0[i*DF + 4*q+2], acc.z);
      acc.w = fmaf(xi, F0[i*DF + 4*q+3], acc.w);
    }
    orow[q] = acc;
  }
}

// ---------------- edge MLP + segmented reduce ----------------
template <int RBASE, int W>
__device__ inline void accW(float (&h)[HF], const float (&v)[W],
                            const float* __restrict__ W1) {
#pragma unroll 4
  for (int ii = 0; ii < W; ++ii) {
    float x = v[ii];
    const float* w = W1 + (RBASE + ii) * HF;
#pragma unroll
    for (int j = 0; j < HF; ++j) h[j] = fmaf(x, w[j], h[j]);
  }
}

__global__ __launch_bounds__(256) void edge_kernel(
    const float* __restrict__ x_s, const float* __restrict__ outp,
    const float* __restrict__ ea,
    const int* __restrict__ row_s, const int* __restrict__ col_s,
    const int* __restrict__ eid_s,
    const float* __restrict__ W1, const float* __restrict__ b1,
    const float* __restrict__ W2, const float* __restrict__ b2,
    float* __restrict__ scattered) {
  __shared__ float sh[256 * 33];
  __shared__ int scol[256];
  __shared__ int lst0[256];
  __shared__ int lst1[256];
  __shared__ int wbase[4];
  __shared__ int cnt;
  int tid = threadIdx.x;
  int i = blockIdx.x * 256 + tid;
  if (tid == 0) cnt = 0;
  int c_self = -1;
  if (i < NE) {
    int r = row_s[i];
    int c = col_s[i];
    int e = eid_s[i];
    c_self = c;
    float h[HF];
#pragma unroll
    for (int j = 0; j < HF; ++j) h[j] = b1[j];
    float sr = 0.f, sc = 0.f;
    {  // xs_row -> rows 0..15
      float v[16];
      const float4* p = (const float4*)(x_s + (size_t)r * SF);
#pragma unroll
      for (int q = 0; q < 4; ++q) {
        float4 t = p[q];
        v[4*q]=t.x; v[4*q+1]=t.y; v[4*q+2]=t.z; v[4*q+3]=t.w;
      }
      accW<0, 16>(h, v, W1);
    }
    {  // xs_col -> rows 16..31
      float v[16];
      const float4* p = (const float4*)(x_s + (size_t)c * SF);
#pragma unroll
      for (int q = 0; q < 4; ++q) {
        float4 t = p[q];
        v[4*q]=t.x; v[4*q+1]=t.y; v[4*q+2]=t.z; v[4*q+3]=t.w;
      }
      accW<16, 16>(h, v, W1);
    }
    {  // out_row -> rows 32..63 (two 16-chunks), also sr
      const float4* p = (const float4*)(outp + (size_t)r * DF);
      float v[16];
#pragma unroll
      for (int q = 0; q < 4; ++q) {
        float4 t = p[q];
        v[4*q]=t.x; v[4*q+1]=t.y; v[4*q+2]=t.z; v[4*q+3]=t.w;
        sr += t.x + t.y + t.z + t.w;
      }
      accW<32, 16>(h, v, W1);
#pragma unroll
      for (int q = 0; q < 4; ++q) {
        float4 t = p[4 + q];
        v[4*q]=t.x; v[4*q+1]=t.y; v[4*q+2]=t.z; v[4*q+3]=t.w;
        sr += t.x + t.y + t.z + t.w;
      }
      accW<48, 16>(h, v, W1);
    }
    {  // out_col -> rows 64..95, also sc
      const float4* p = (const float4*)(outp + (size_t)c * DF);
      float v[16];
#pragma unroll
      for (int q = 0; q < 4; ++q) {
        float4 t = p[q];
        v[4*q]=t.x; v[4*q+1]=t.y; v[4*q+2]=t.z; v[4*q+3]=t.w;
        sc += t.x + t.y + t.z + t.w;
      }
      accW<64, 16>(h, v, W1);
#pragma unroll
      for (int q = 0; q < 4; ++q) {
        float4 t = p[4 + q];
        v[4*q]=t.x; v[4*q+1]=t.y; v[4*q+2]=t.z; v[4*q+3]=t.w;
        sc += t.x + t.y + t.z + t.w;
      }
      accW<80, 16>(h, v, W1);
    }
    {  // edge_attr -> rows 96..103
      float v[8];
      const float4* p = (const float4*)(ea + (size_t)e * EFT);
#pragma unroll
      for (int q = 0; q < 2; ++q) {
        float4 t = p[q];
        v[4*q]=t.x; v[4*q+1]=t.y; v[4*q+2]=t.z; v[4*q+3]=t.w;
      }
      accW<96, 8>(h, v, W1);
    }
    // layer 2
    float o[DF];
#pragma unroll
    for (int j = 0; j < DF; ++j) o[j] = b2[j];
#pragma unroll 2
    for (int jj = 0; jj < HF; ++jj) {
      float hr = fmaxf(h[jj], 0.f);
      const float* w = W2 + jj * DF;
#pragma unroll
      for (int j = 0; j < DF; ++j) o[j] = fmaf(hr, w[j], o[j]);
    }
    float nsq = 0.f;
#pragma unroll
    for (int j = 0; j < DF; ++j) nsq = fmaf(o[j], o[j], nsq);
    float ms = (nsq > 0.f) ? rsqrtf(nsq) : 0.f;
    if (sr == 0.f && sc == 0.f) ms = 0.f;
    // reload out rows from cache, write shift into LDS
    const float4* pr = (const float4*)(outp + (size_t)r * DF);
    const float4* pc = (const float4*)(outp + (size_t)c * DF);
    float* shp = sh + tid * 33;
#pragma unroll
    for (int q = 0; q < 8; ++q) {
      float4 a = pr[q];
      float4 b = pc[q];
      shp[4*q+0] = (b.x - a.x) * o[4*q+0] * ms;
      shp[4*q+1] = (b.y - a.y) * o[4*q+1] * ms;
      shp[4*q+2] = (b.z - a.z) * o[4*q+2] * ms;
      shp[4*q+3] = (b.w - a.w) * o[4*q+3] * ms;
    }
  } else {
    float* shp = sh + tid * 33;
#pragma unroll
    for (int j = 0; j < 32; ++j) shp[j] = 0.f;
  }
  scol[tid] = c_self;
  __syncthreads();
  bool head = (c_self >= 0) && (tid == 0 || scol[tid - 1] != c_self);
  unsigned long long m = __ballot(head);
  int lane = tid & 63, wid = tid >> 6;
  if (lane == 0) wbase[wid] = atomicAdd(&cnt, (int)__popcll(m));
  __syncthreads();
  if (head) {
    int idx = wbase[wid] + (int)__popcll(m & ((1ull << lane) - 1ull));
    int t1 = tid + 1;
    while (t1 < 256 && scol[t1] == c_self) ++t1;
    lst0[idx] = tid;
    lst1[idx] = t1;
  }
  __syncthreads();
  int nr = cnt;
  for (int task = tid; task < nr * 32; task += 256) {
    int rid = task >> 5, j = task & 31;
    int t0 = lst0[rid], t1 = lst1[rid];
    float s = 0.f;
    for (int t = t0; t < t1; ++t) s += sh[t * 33 + j];
    unsafeAtomicAdd(&scattered[(size_t)scol[t0] * DF + j], s);
  }
}

// ------------- node update: outn = outp + scattered @ Fk; scattered = 0 ----
__global__ __launch_bounds__(256) void node_kernel(
    const float* __restrict__ outp, float* __restrict__ outn,
    float* __restrict__ scattered, const float* __restrict__ Fk) {
  int n = blockIdx.x * 256 + threadIdx.x;
  if (n >= NN) return;
  float s[DF];
  float4* sp = reinterpret_cast<float4*>(scattered + (size_t)n * DF);
#pragma unroll
  for (int q = 0; q < 8; ++q) {
    float4 v = sp[q];
    s[4*q+0]=v.x; s[4*q+1]=v.y; s[4*q+2]=v.z; s[4*q+3]=v.w;
  }
  const float4* ip = reinterpret_cast<const float4*>(outp + (size_t)n * DF);
  float4* op = reinterpret_cast<float4*>(outn + (size_t)n * DF);
#pragma unroll
  for (int q = 0; q < 8; ++q) {
    float4 acc = ip[q];
#pragma unroll
    for (int i = 0; i < DF; ++i) {
      float si = s[i];
      acc.x = fmaf(si, Fk[i*DF + 4*q+0], acc.x);
      acc.y = fmaf(si, Fk[i*DF + 4*q+1], acc.y);
      acc.z = fmaf(si, Fk[i*DF + 4*q+2], acc.z);
      acc.w = fmaf(si, Fk[i*DF + 4*q+3], acc.w);
    }
    op[q] = acc;
  }
  float4 z = {0.f, 0.f, 0.f, 0.f};
#pragma unroll
  for (int q = 0; q < 8; ++q) sp[q] = z;
}

extern "C" void kernel_launch(void* const* d_in, const int* in_sizes, int n_in,
                              void* d_out, int out_size, void* d_ws, size_t ws_size,
                              hipStream_t stream) {
  const float* x_s = (const float*)d_in[0];
  const float* x_t = (const float*)d_in[1];
  const int*   ei  = (const int*)d_in[2];
  const float* ea  = (const float*)d_in[3];
  const float* W1  = (const float*)d_in[4];
  const float* b1  = (const float*)d_in[5];
  const float* W2  = (const float*)d_in[6];
  const float* b2  = (const float*)d_in[7];
  const float* F   = (const float*)d_in[8];

  float* out = (float*)d_out;
  char* ws = (char*)d_ws;
  float* scattered = (float*)(ws + 0);           // 12.8 MB
  float* buf1      = (float*)(ws + 12800000);    // 12.8 MB
  int*   row_s     = (int*)(ws + 25600000);      // 6.4 MB
  int*   col_s     = (int*)(ws + 32000000);      // 6.4 MB
  int*   eid_s     = (int*)(ws + 38400000);      // 6.4 MB
  int*   deg       = (int*)(ws + 44800000);      // 0.4 MB
  int*   cur       = (int*)(ws + 45200000);      // 0.4 MB
  int*   bsums     = (int*)(ws + 45600000);      // 2 KB

  hipMemsetAsync(deg, 0, NN * sizeof(int), stream);
  hipMemsetAsync(scattered, 0, (size_t)NN * DF * sizeof(float), stream);

  dim3 blk(256);
  dim3 grid_e((NE + 255) / 256);
  dim3 grid_n((NN + 255) / 256);
  int nscan = (NN + 1023) / 1024;

  hist_kernel<<<grid_e, blk, 0, stream>>>(ei, deg);
  scan1_kernel<<<nscan, blk, 0, stream>>>(deg, cur, bsums);
  scan2_kernel<<<1, 1, 0, stream>>>(bsums, nscan);
  scan3_kernel<<<grid_n, blk, 0, stream>>>(cur, bsums);
  fill_kernel<<<grid_e, blk, 0, stream>>>(ei, cur, row_s, col_s, eid_s);

  init_kernel<<<grid_n, blk, 0, stream>>>(x_t, F, out);

  // k = 0: read out (d_out), write buf1
  edge_kernel<<<grid_e, blk, 0, stream>>>(x_s, out, ea, row_s, col_s, eid_s,
                                          W1, b1, W2, b2, scattered);
  node_kernel<<<grid_n, blk, 0, stream>>>(out, buf1, scattered,
                                          F + (size_t)1 * DF * DF);
  // k = 1: read buf1, write d_out
  edge_kernel<<<grid_e, blk, 0, stream>>>(x_s, buf1, ea, row_s, col_s, eid_s,
                                          W1, b1, W2, b2, scattered);
  node_kernel<<<grid_n, blk, 0, stream>>>(buf1, out, scattered,
                                          F + (size_t)2 * DF * DF);
}

// Round 3
// 743.960 us; speedup vs baseline: 10.8807x; 2.0779x over previous
//
#include <hip/hip_runtime.h>

#define NN 100000
#define NE 1600000
#define SF 16
#define DF 32
#define EFT 8
#define HF 64

// ---------------- CSR build ----------------
__global__ __launch_bounds__(256) void hist_kernel(const int* __restrict__ ei,
                                                   int* __restrict__ deg) {
  int e = blockIdx.x * 256 + threadIdx.x;
  if (e < NE) atomicAdd(&deg[ei[NE + e]], 1);
}

__global__ __launch_bounds__(256) void scan1_kernel(const int* __restrict__ deg,
                                                    int* __restrict__ cur,
                                                    int* __restrict__ bsums) {
  __shared__ int ts[256];
  int tid = threadIdx.x;
  int base = blockIdx.x * 1024 + tid * 4;
  int v[4];
#pragma unroll
  for (int q = 0; q < 4; ++q) v[q] = (base + q < NN) ? deg[base + q] : 0;
  int s = v[0] + v[1] + v[2] + v[3];
  ts[tid] = s;
  __syncthreads();
  for (int off = 1; off < 256; off <<= 1) {
    int t = (tid >= off) ? ts[tid - off] : 0;
    __syncthreads();
    ts[tid] += t;
    __syncthreads();
  }
  int excl = ts[tid] - s;
  if (tid == 255) bsums[blockIdx.x] = ts[255];
  int run = excl;
#pragma unroll
  for (int q = 0; q < 4; ++q) {
    if (base + q < NN) cur[base + q] = run;
    run += v[q];
  }
}

__global__ void scan2_kernel(int* __restrict__ bsums, int nb) {
  int acc = 0;
  for (int i = 0; i < nb; ++i) { int t = bsums[i]; bsums[i] = acc; acc += t; }
}

__global__ __launch_bounds__(256) void scan3_kernel(int* __restrict__ cur,
                                                    const int* __restrict__ bsums) {
  int i = blockIdx.x * 256 + threadIdx.x;
  if (i < NN) cur[i] += bsums[i >> 10];
}

__global__ __launch_bounds__(256) void fill_kernel(const int* __restrict__ ei,
                                                   int* __restrict__ cur,
                                                   int* __restrict__ row_s,
                                                   int* __restrict__ col_s,
                                                   int* __restrict__ eid_s) {
  int e = blockIdx.x * 256 + threadIdx.x;
  if (e >= NE) return;
  int r = ei[e];
  int c = ei[NE + e];
  int pos = atomicAdd(&cur[c], 1);
  row_s[pos] = r;
  col_s[pos] = c;
  eid_s[pos] = e;
}

// ---------------- init: out = x_t @ F[0] ----------------
__global__ __launch_bounds__(256) void init_kernel(
    const float* __restrict__ x_t, const float* __restrict__ F0,
    float* __restrict__ out) {
  int n = blockIdx.x * 256 + threadIdx.x;
  if (n >= NN) return;
  float x[DF];
  const float4* xr = reinterpret_cast<const float4*>(x_t + (size_t)n * DF);
#pragma unroll
  for (int q = 0; q < 8; ++q) {
    float4 v = xr[q];
    x[4*q+0]=v.x; x[4*q+1]=v.y; x[4*q+2]=v.z; x[4*q+3]=v.w;
  }
  float4* orow = reinterpret_cast<float4*>(out + (size_t)n * DF);
#pragma unroll
  for (int q = 0; q < 8; ++q) {
    float4 acc = {0.f, 0.f, 0.f, 0.f};
#pragma unroll
    for (int i = 0; i < DF; ++i) {
      float xi = x[i];
      acc.x = fmaf(xi, F0[i*DF + 4*q+0], acc.x);
      acc.y = fmaf(xi, F0[i*DF + 4*q+1], acc.y);
      acc.z = fmaf(xi, F0[i*DF + 4*q+2], acc.z);
      acc.w = fmaf(xi, F0[i*DF + 4*q+3], acc.w);
    }
    orow[q] = acc;
  }
}

// ------- per-node precompute: A = xs@W1[0:16]+out@W1[32:64],
//         B = xs@W1[16:32]+out@W1[64:96]; sums = rowsum(out) -------
__global__ __launch_bounds__(256) void pre_kernel(
    const float* __restrict__ x_s, const float* __restrict__ outp,
    const float* __restrict__ W1, float* __restrict__ AB,
    float* __restrict__ sums) {
  int n = blockIdx.x * 256 + threadIdx.x;
  if (n >= NN) return;
  float xs[SF];
  {
    const float4* p = (const float4*)(x_s + (size_t)n * SF);
#pragma unroll
    for (int q = 0; q < 4; ++q) {
      float4 v = p[q];
      xs[4*q]=v.x; xs[4*q+1]=v.y; xs[4*q+2]=v.z; xs[4*q+3]=v.w;
    }
  }
  float ot[DF];
  float s = 0.f;
  {
    const float4* p = (const float4*)(outp + (size_t)n * DF);
#pragma unroll
    for (int q = 0; q < 8; ++q) {
      float4 v = p[q];
      ot[4*q]=v.x; ot[4*q+1]=v.y; ot[4*q+2]=v.z; ot[4*q+3]=v.w;
      s += v.x + v.y + v.z + v.w;
    }
  }
  sums[n] = s;
  float* abp = AB + (size_t)n * 128;
  // A half (stored at +0): xs rows 0..15, out rows 32..63
#pragma unroll 1
  for (int ch = 0; ch < 4; ++ch) {
    float acc[16];
#pragma unroll
    for (int j = 0; j < 16; ++j) acc[j] = 0.f;
#pragma unroll
    for (int i = 0; i < SF; ++i) {
      float x = xs[i];
      const float* w = W1 + i * HF + ch * 16;
#pragma unroll
      for (int j = 0; j < 16; ++j) acc[j] = fmaf(x, w[j], acc[j]);
    }
#pragma unroll
    for (int i = 0; i < DF; ++i) {
      float x = ot[i];
      const float* w = W1 + (32 + i) * HF + ch * 16;
#pragma unroll
      for (int j = 0; j < 16; ++j) acc[j] = fmaf(x, w[j], acc[j]);
    }
    float4* st = (float4*)(abp + ch * 16);
#pragma unroll
    for (int q = 0; q < 4; ++q) {
      float4 v = {acc[4*q], acc[4*q+1], acc[4*q+2], acc[4*q+3]};
      st[q] = v;
    }
  }
  // B half (stored at +64): xs rows 16..31, out rows 64..95
#pragma unroll 1
  for (int ch = 0; ch < 4; ++ch) {
    float acc[16];
#pragma unroll
    for (int j = 0; j < 16; ++j) acc[j] = 0.f;
#pragma unroll
    for (int i = 0; i < SF; ++i) {
      float x = xs[i];
      const float* w = W1 + (16 + i) * HF + ch * 16;
#pragma unroll
      for (int j = 0; j < 16; ++j) acc[j] = fmaf(x, w[j], acc[j]);
    }
#pragma unroll
    for (int i = 0; i < DF; ++i) {
      float x = ot[i];
      const float* w = W1 + (64 + i) * HF + ch * 16;
#pragma unroll
      for (int j = 0; j < 16; ++j) acc[j] = fmaf(x, w[j], acc[j]);
    }
    float4* st = (float4*)(abp + 64 + ch * 16);
#pragma unroll
    for (int q = 0; q < 4; ++q) {
      float4 v = {acc[4*q], acc[4*q+1], acc[4*q+2], acc[4*q+3]};
      st[q] = v;
    }
  }
}

// ---------------- edge MLP + segmented reduce ----------------
__global__ __launch_bounds__(256, 4) void edge_kernel(
    const float* __restrict__ AB, const float* __restrict__ outp,
    const float* __restrict__ sums, const float* __restrict__ ea,
    const int* __restrict__ row_s, const int* __restrict__ col_s,
    const int* __restrict__ eid_s,
    const float* __restrict__ W1, const float* __restrict__ b1,
    const float* __restrict__ W2, const float* __restrict__ b2,
    float* __restrict__ scattered) {
  __shared__ float sh[256 * 33];
  __shared__ int scol[256];
  __shared__ int lst0[256];
  __shared__ int lst1[256];
  __shared__ int wbase[4];
  __shared__ int cnt;
  int tid = threadIdx.x;
  int i = blockIdx.x * 256 + tid;
  if (tid == 0) cnt = 0;
  int c_self = -1;
  if (i < NE) {
    int r = row_s[i];
    int c = col_s[i];
    int e = eid_s[i];
    c_self = c;
    float eav[8];
    {
      const float4* p = (const float4*)(ea + (size_t)e * EFT);
      float4 v0 = p[0], v1 = p[1];
      eav[0]=v0.x; eav[1]=v0.y; eav[2]=v0.z; eav[3]=v0.w;
      eav[4]=v1.x; eav[5]=v1.y; eav[6]=v1.z; eav[7]=v1.w;
    }
    float o[DF];
#pragma unroll
    for (int j = 0; j < DF; ++j) o[j] = b2[j];
    const float* ar = AB + (size_t)r * 128;
    const float* bc = AB + (size_t)c * 128 + 64;
#pragma unroll 2
    for (int ch = 0; ch < 8; ++ch) {
      float4 a0 = *(const float4*)(ar + ch * 8);
      float4 a1 = *(const float4*)(ar + ch * 8 + 4);
      float4 b0 = *(const float4*)(bc + ch * 8);
      float4 b1v = *(const float4*)(bc + ch * 8 + 4);
      float av[8] = {a0.x, a0.y, a0.z, a0.w, a1.x, a1.y, a1.z, a1.w};
      float bv[8] = {b0.x, b0.y, b0.z, b0.w, b1v.x, b1v.y, b1v.z, b1v.w};
#pragma unroll
      for (int jj = 0; jj < 8; ++jj) {
        float cj = b1[ch * 8 + jj];
#pragma unroll
        for (int t = 0; t < 8; ++t)
          cj = fmaf(eav[t], W1[(96 + t) * HF + ch * 8 + jj], cj);
        float h = fmaxf(av[jj] + bv[jj] + cj, 0.f);
        const float* w2r = W2 + (ch * 8 + jj) * DF;
#pragma unroll
        for (int j = 0; j < DF; ++j) o[j] = fmaf(h, w2r[j], o[j]);
      }
    }
    float nsq = 0.f;
#pragma unroll
    for (int j = 0; j < DF; ++j) nsq = fmaf(o[j], o[j], nsq);
    float ms = (nsq > 0.f) ? rsqrtf(nsq) : 0.f;
    float s_r = sums[r], s_c = sums[c];
    if (s_r == 0.f && s_c == 0.f) ms = 0.f;
    const float4* pr = (const float4*)(outp + (size_t)r * DF);
    const float4* pc = (const float4*)(outp + (size_t)c * DF);
    float* shp = sh + tid * 33;
#pragma unroll
    for (int q = 0; q < 8; ++q) {
      float4 a = pr[q];
      float4 b = pc[q];
      shp[4*q+0] = (b.x - a.x) * o[4*q+0] * ms;
      shp[4*q+1] = (b.y - a.y) * o[4*q+1] * ms;
      shp[4*q+2] = (b.z - a.z) * o[4*q+2] * ms;
      shp[4*q+3] = (b.w - a.w) * o[4*q+3] * ms;
    }
  }
  scol[tid] = c_self;
  __syncthreads();
  bool head = (c_self >= 0) && (tid == 0 || scol[tid - 1] != c_self);
  unsigned long long m = __ballot(head);
  int lane = tid & 63, wid = tid >> 6;
  if (lane == 0) wbase[wid] = atomicAdd(&cnt, (int)__popcll(m));
  __syncthreads();
  if (head) {
    int idx = wbase[wid] + (int)__popcll(m & ((1ull << lane) - 1ull));
    int t1 = tid + 1;
    while (t1 < 256 && scol[t1] == c_self) ++t1;
    lst0[idx] = tid;
    lst1[idx] = t1;
  }
  __syncthreads();
  int nr = cnt;
  for (int task = tid; task < nr * 32; task += 256) {
    int rid = task >> 5, j = task & 31;
    int t0 = lst0[rid], t1 = lst1[rid];
    float s = 0.f;
    for (int t = t0; t < t1; ++t) s += sh[t * 33 + j];
    unsafeAtomicAdd(&scattered[(size_t)scol[t0] * DF + j], s);
  }
}

// ------- node update (in place): out += scattered @ Fk; scattered = 0 -------
__global__ __launch_bounds__(256) void node_kernel(
    float* __restrict__ out, float* __restrict__ scattered,
    const float* __restrict__ Fk) {
  int n = blockIdx.x * 256 + threadIdx.x;
  if (n >= NN) return;
  float s[DF];
  float4* sp = reinterpret_cast<float4*>(scattered + (size_t)n * DF);
#pragma unroll
  for (int q = 0; q < 8; ++q) {
    float4 v = sp[q];
    s[4*q+0]=v.x; s[4*q+1]=v.y; s[4*q+2]=v.z; s[4*q+3]=v.w;
  }
  float4* op = reinterpret_cast<float4*>(out + (size_t)n * DF);
#pragma unroll
  for (int q = 0; q < 8; ++q) {
    float4 acc = op[q];
#pragma unroll
    for (int i = 0; i < DF; ++i) {
      float si = s[i];
      acc.x = fmaf(si, Fk[i*DF + 4*q+0], acc.x);
      acc.y = fmaf(si, Fk[i*DF + 4*q+1], acc.y);
      acc.z = fmaf(si, Fk[i*DF + 4*q+2], acc.z);
      acc.w = fmaf(si, Fk[i*DF + 4*q+3], acc.w);
    }
    op[q] = acc;
  }
  float4 z = {0.f, 0.f, 0.f, 0.f};
#pragma unroll
  for (int q = 0; q < 8; ++q) sp[q] = z;
}

extern "C" void kernel_launch(void* const* d_in, const int* in_sizes, int n_in,
                              void* d_out, int out_size, void* d_ws, size_t ws_size,
                              hipStream_t stream) {
  const float* x_s = (const float*)d_in[0];
  const float* x_t = (const float*)d_in[1];
  const int*   ei  = (const int*)d_in[2];
  const float* ea  = (const float*)d_in[3];
  const float* W1  = (const float*)d_in[4];
  const float* b1  = (const float*)d_in[5];
  const float* W2  = (const float*)d_in[6];
  const float* b2  = (const float*)d_in[7];
  const float* F   = (const float*)d_in[8];

  float* out = (float*)d_out;
  char* ws = (char*)d_ws;
  float* scattered = (float*)(ws + 0);           // 12.8 MB
  float* AB        = (float*)(ws + 12800000);    // 51.2 MB (100K x 128 f32)
  float* sums      = (float*)(ws + 64000000);    // 0.4 MB
  int*   row_s     = (int*)(ws + 64400000);      // 6.4 MB
  int*   col_s     = (int*)(ws + 70800000);      // 6.4 MB
  int*   eid_s     = (int*)(ws + 77200000);      // 6.4 MB
  int*   deg       = (int*)(ws + 83600000);      // 0.4 MB
  int*   cur       = (int*)(ws + 84000000);      // 0.4 MB
  int*   bsums     = (int*)(ws + 84400000);      // 2 KB

  hipMemsetAsync(deg, 0, NN * sizeof(int), stream);
  hipMemsetAsync(scattered, 0, (size_t)NN * DF * sizeof(float), stream);

  dim3 blk(256);
  dim3 grid_e((NE + 255) / 256);
  dim3 grid_n((NN + 255) / 256);
  int nscan = (NN + 1023) / 1024;

  hist_kernel<<<grid_e, blk, 0, stream>>>(ei, deg);
  scan1_kernel<<<nscan, blk, 0, stream>>>(deg, cur, bsums);
  scan2_kernel<<<1, 1, 0, stream>>>(bsums, nscan);
  scan3_kernel<<<grid_n, blk, 0, stream>>>(cur, bsums);
  fill_kernel<<<grid_e, blk, 0, stream>>>(ei, cur, row_s, col_s, eid_s);

  init_kernel<<<grid_n, blk, 0, stream>>>(x_t, F, out);

  for (int k = 0; k < 2; ++k) {
    pre_kernel<<<grid_n, blk, 0, stream>>>(x_s, out, W1, AB, sums);
    edge_kernel<<<grid_e, blk, 0, stream>>>(AB, out, sums, ea,
                                            row_s, col_s, eid_s,
                                            W1, b1, W2, b2, scattered);
    node_kernel<<<grid_n, blk, 0, stream>>>(out, scattered,
                                            F + (size_t)(k + 1) * DF * DF);
  }
}